// Round 1
// baseline (1764.300 us; speedup 1.0000x reference)
//
#include <hip/hip_runtime.h>

// WindowAttention (Swin-style) on gfx950.
// Pipeline: [conv x->bf16] [transpose w->bf16] [GEMM qkv] [attn per (b,h)] [GEMM proj]
// R0: correctness-first bf16 MFMA pipeline. ws layout:
//   0         : x_bf16 [100352][512]  (102,760,448 B) -- reused as attn_out bf16
//   102760448 : qkv    [100352][1536] (308,281,344 B)
//   411041792 : wqkv_t [1536][512]    (1,572,864 B)
//   412614656 : wproj_t[512][512]     (524,288 B)     total ~413.1 MB

typedef unsigned short u16;
typedef __attribute__((ext_vector_type(8))) short short8;
typedef __attribute__((ext_vector_type(4))) float floatx4;

#define B_WIN 2048
#define SEQ 49
#define DIM 512
#define NHEAD 16
#define HD 32
#define MROWS (B_WIN * SEQ)   // 100352

__device__ __forceinline__ u16 f2bf(float x) {
    unsigned u = __float_as_uint(x);
    u += 0x7fffu + ((u >> 16) & 1u);   // RNE
    return (u16)(u >> 16);
}

__device__ __forceinline__ void async_ld16(const void* g, void* l) {
    __builtin_amdgcn_global_load_lds(
        (const __attribute__((address_space(1))) void*)g,
        (__attribute__((address_space(3))) void*)l, 16, 0, 0);
}

// ---------- conversion kernels ----------
__global__ void conv_f32_bf16(const float* __restrict__ in, u16* __restrict__ out, int n4) {
    int id = blockIdx.x * 256 + threadIdx.x;
    if (id >= n4) return;
    float4 v = ((const float4*)in)[id];
    uint2 o;
    o.x = (unsigned)f2bf(v.x) | ((unsigned)f2bf(v.y) << 16);
    o.y = (unsigned)f2bf(v.z) | ((unsigned)f2bf(v.w) << 16);
    *(uint2*)(out + (size_t)id * 4) = o;
}

// in: [512][Cn] f32 (k-major). out: [Cn][512] bf16 (n-major).
__global__ void transpose_conv(const float* __restrict__ in, u16* __restrict__ out, int Cn) {
    int id = blockIdx.x * 256 + threadIdx.x;
    if (id >= Cn * 512) return;
    int k = id & 511;
    int n = id >> 9;
    out[id] = f2bf(in[(size_t)k * Cn + n]);
}

// ---------- GEMM: C[M][N] = A[M][K](bf16) * Bt[N][K](bf16)^T + bias ----------
template<bool STORE_BF16>
__global__ __launch_bounds__(256, 2)
void gemm_bt(const u16* __restrict__ A, const u16* __restrict__ Bt,
             const float* __restrict__ bias, void* __restrict__ Cout,
             int M, int N, int K) {
    const int tid  = threadIdx.x;
    const int lane = tid & 63, wave = tid >> 6;
    const int quad = lane >> 4, l16 = lane & 15;
    const int wr = wave >> 1, wc = wave & 1;
    const int m0 = blockIdx.y * 128, n0 = blockIdx.x * 128;

    __shared__ u16 As[128 * 32];
    __shared__ u16 Bs[128 * 32];

    // staging map: 8 chunks of 64 lanes x 16B; tile is row-major [128][32] bf16
    const int f0 = (wave * 2 + 0) * 512 + lane * 8;
    const int f1 = (wave * 2 + 1) * 512 + lane * 8;
    const int r0 = f0 >> 5, c0 = f0 & 31;
    const int r1 = f1 >> 5, c1 = f1 & 31;
    const u16* Ab = A + (size_t)m0 * K;
    const u16* Bb = Bt + (size_t)n0 * K;

    floatx4 acc[4][4] = {};

    for (int kt = 0; kt < K; kt += 32) {
        async_ld16(Ab + (size_t)r0 * K + kt + c0, &As[f0]);
        async_ld16(Ab + (size_t)r1 * K + kt + c1, &As[f1]);
        async_ld16(Bb + (size_t)r0 * K + kt + c0, &Bs[f0]);
        async_ld16(Bb + (size_t)r1 * K + kt + c1, &Bs[f1]);
        __syncthreads();
        short8 af[4], bf[4];
#pragma unroll
        for (int i = 0; i < 4; ++i)
            af[i] = *(const short8*)&As[(wr * 64 + i * 16 + l16) * 32 + quad * 8];
#pragma unroll
        for (int j = 0; j < 4; ++j)
            bf[j] = *(const short8*)&Bs[(wc * 64 + j * 16 + l16) * 32 + quad * 8];
#pragma unroll
        for (int i = 0; i < 4; ++i)
#pragma unroll
            for (int j = 0; j < 4; ++j)
                acc[i][j] = __builtin_amdgcn_mfma_f32_16x16x32_bf16(af[i], bf[j], acc[i][j], 0, 0, 0);
        __syncthreads();
    }

#pragma unroll
    for (int i = 0; i < 4; ++i) {
#pragma unroll
        for (int j = 0; j < 4; ++j) {
            int col = n0 + wc * 64 + j * 16 + l16;
            float bv = bias[col];
#pragma unroll
            for (int r = 0; r < 4; ++r) {
                int row = m0 + wr * 64 + i * 16 + quad * 4 + r;
                float val = acc[i][j][r] + bv;
                size_t off = (size_t)row * N + col;
                if (STORE_BF16) ((u16*)Cout)[off] = f2bf(val);
                else            ((float*)Cout)[off] = val;
            }
        }
    }
}

// ---------- attention: one wave per (window b, head h) ----------
__global__ __launch_bounds__(64)
void attn_kernel(const u16* __restrict__ qkv, const float* __restrict__ mask,
                 const float* __restrict__ bias_table, const int* __restrict__ rel_idx,
                 u16* __restrict__ attn_out) {
    const int bid = blockIdx.x;
    const int b = bid >> 4, h = bid & 15;
    const int lane = threadIdx.x;
    const int quad = lane >> 4, l16 = lane & 15;

    __shared__ u16 qs[64 * 32];     // [m][k] bf16, rows >=49 zero
    __shared__ u16 ks[64 * 32];     // [n][k] bf16, rows >=49 zero
    __shared__ u16 vt[32 * 64];     // [d][s] bf16, cols s>=49 zero
    __shared__ float lg[49 * 52];   // logits
    __shared__ u16 ps[64 * 64];     // probs bf16 [m][k], pad zero

    // zero pad-sensitive buffers
    {
        int4 z = {0, 0, 0, 0};
        int4* pq = (int4*)qs; int4* pk = (int4*)ks; int4* pv = (int4*)vt;
#pragma unroll
        for (int i = lane; i < 256; i += 64) { pq[i] = z; pk[i] = z; pv[i] = z; }
        int4* pp = (int4*)ps;
#pragma unroll
        for (int i = lane; i < 512; i += 64) pp[i] = z;
    }
    __syncthreads();

    // load q,k,v for this (b,h). qkv row s: col = c*512 + h*32 + d
    const u16* base = qkv + (size_t)b * SEQ * 1536 + h * HD;
    for (int c = lane; c < 196; c += 64) {      // 196 = 49 rows * 4 chunks of 8
        int s = c >> 2, d0 = (c & 3) * 8;
        int4 qv = *(const int4*)(base + (size_t)s * 1536 + d0);
        *(int4*)&qs[s * 32 + d0] = qv;
        int4 kv = *(const int4*)(base + (size_t)s * 1536 + 512 + d0);
        *(int4*)&ks[s * 32 + d0] = kv;
        int4 vv = *(const int4*)(base + (size_t)s * 1536 + 1024 + d0);
        const u16* vsrc = (const u16*)&vv;
#pragma unroll
        for (int e = 0; e < 8; ++e) vt[(d0 + e) * 64 + s] = vsrc[e];
    }
    __syncthreads();

    // QK^T : 4x4 tiles of 16x16, K=32 (one MFMA each)
    floatx4 accS[4][4] = {};
    {
        short8 qf[4], kf[4];
#pragma unroll
        for (int i = 0; i < 4; ++i) qf[i] = *(const short8*)&qs[(i * 16 + l16) * 32 + quad * 8];
#pragma unroll
        for (int j = 0; j < 4; ++j) kf[j] = *(const short8*)&ks[(j * 16 + l16) * 32 + quad * 8];
#pragma unroll
        for (int i = 0; i < 4; ++i)
#pragma unroll
            for (int j = 0; j < 4; ++j)
                accS[i][j] = __builtin_amdgcn_mfma_f32_16x16x32_bf16(qf[i], kf[j], accS[i][j], 0, 0, 0);
    }

    const float scale = 0.1767766952966369f;  // 32^-0.5
    const float* mrow = mask + (size_t)(b & 63) * (SEQ * SEQ);
#pragma unroll
    for (int i = 0; i < 4; ++i)
#pragma unroll
        for (int j = 0; j < 4; ++j) {
            int col = j * 16 + l16;
#pragma unroll
            for (int r = 0; r < 4; ++r) {
                int row = i * 16 + quad * 4 + r;
                if (row < SEQ && col < SEQ) {
                    int t = rel_idx[row * SEQ + col];
                    lg[row * 52 + col] = accS[i][j][r] * scale + bias_table[t * NHEAD + h]
                                       + mrow[row * SEQ + col];
                }
            }
        }
    __syncthreads();

    // softmax: cooperative per row (lane j handles col j)
    for (int row = 0; row < SEQ; ++row) {
        float x = (lane < SEQ) ? lg[row * 52 + lane] : -3.0e38f;
        float m = x;
#pragma unroll
        for (int off = 32; off; off >>= 1) m = fmaxf(m, __shfl_xor(m, off));
        float e = (lane < SEQ) ? __expf(x - m) : 0.f;
        float ssum = e;
#pragma unroll
        for (int off = 32; off; off >>= 1) ssum += __shfl_xor(ssum, off);
        if (lane < SEQ) ps[row * 64 + lane] = f2bf(e / ssum);
    }
    __syncthreads();

    // PV : P[64x64(pad0)] x V[64x32] ; 4 m-tiles x 2 n-tiles x 2 k-steps
    floatx4 accO[4][2] = {};
#pragma unroll
    for (int kt = 0; kt < 2; ++kt) {
        short8 pf[4], vf[2];
#pragma unroll
        for (int i = 0; i < 4; ++i)
            pf[i] = *(const short8*)&ps[(i * 16 + l16) * 64 + kt * 32 + quad * 8];
#pragma unroll
        for (int jn = 0; jn < 2; ++jn)
            vf[jn] = *(const short8*)&vt[(jn * 16 + l16) * 64 + kt * 32 + quad * 8];
#pragma unroll
        for (int i = 0; i < 4; ++i)
#pragma unroll
            for (int jn = 0; jn < 2; ++jn)
                accO[i][jn] = __builtin_amdgcn_mfma_f32_16x16x32_bf16(pf[i], vf[jn], accO[i][jn], 0, 0, 0);
    }

    u16* op = attn_out + (size_t)b * SEQ * DIM + h * HD;
#pragma unroll
    for (int i = 0; i < 4; ++i)
#pragma unroll
        for (int jn = 0; jn < 2; ++jn)
#pragma unroll
            for (int r = 0; r < 4; ++r) {
                int row = i * 16 + quad * 4 + r;
                if (row < SEQ) op[(size_t)row * DIM + jn * 16 + l16] = f2bf(accO[i][jn][r]);
            }
}

extern "C" void kernel_launch(void* const* d_in, const int* in_sizes, int n_in,
                              void* d_out, int out_size, void* d_ws, size_t ws_size,
                              hipStream_t stream) {
    const float* x         = (const float*)d_in[0];
    const float* mask      = (const float*)d_in[1];
    const float* qkv_w     = (const float*)d_in[2];
    const float* qkv_b     = (const float*)d_in[3];
    const float* proj_w    = (const float*)d_in[4];
    const float* proj_b    = (const float*)d_in[5];
    const float* bias_tab  = (const float*)d_in[6];
    const int*   rel_idx   = (const int*)d_in[7];
    float* out = (float*)d_out;

    char* ws = (char*)d_ws;
    u16* xbf     = (u16*)(ws + 0);            // also attn_out
    u16* qkvbuf  = (u16*)(ws + 102760448);
    u16* wqkv_t  = (u16*)(ws + 411041792);
    u16* wproj_t = (u16*)(ws + 412614656);

    // x -> bf16 (51,380,224 elems = 12,845,056 float4s)
    conv_f32_bf16<<<50176, 256, 0, stream>>>(x, xbf, 12845056);
    // qkv_w [512][1536] -> [1536][512] bf16
    transpose_conv<<<3072, 256, 0, stream>>>(qkv_w, wqkv_t, 1536);
    // proj_w [512][512] -> [512][512]^T bf16
    transpose_conv<<<1024, 256, 0, stream>>>(proj_w, wproj_t, 512);
    // qkv = x @ qkv_w + qkv_b  -> bf16 [100352][1536]
    gemm_bt<true><<<dim3(12, 784), 256, 0, stream>>>(xbf, wqkv_t, qkv_b, qkvbuf,
                                                     MROWS, 1536, 512);
    // attention -> bf16 [100352][512] (reuse xbf)
    attn_kernel<<<B_WIN * NHEAD, 64, 0, stream>>>(qkvbuf, mask, bias_tab, rel_idx, xbf);
    // out = attn @ proj_w + proj_b -> f32
    gemm_bt<false><<<dim3(4, 784), 256, 0, stream>>>(xbf, wproj_t, proj_b, out,
                                                     MROWS, 512, 512);
}

// Round 3
// 939.414 us; speedup vs baseline: 1.8781x; 1.8781x over previous
//
#include <hip/hip_runtime.h>

// WindowAttention (Swin-style) on gfx950 — R3 (R2 memory-layout bugfix).
// Pipeline: [conv x->bf16] [transpose w->bf16] [build_combined]
//           [GEMM qkv -> scattered per-head planes] [attn (reg softmax)] [GEMM proj]
// ws layout (bytes):
//   0          : x_bf16 [100352][512] u16 (102,760,448)  -- reused as attn_out
//   102760448  : qkvp u16:
//                  Q  [b*16+h][49][32]  51,380,224 elems
//                  K  [b*16+h][49][32]  51,380,224 elems  (offset 51380224 elems)
//                  Vt [b*16+h][32][64]  67,108,864 elems  (offset 102760448 elems)
//                total 169,869,312 elems = 339,738,624 B
//   442499072  : combined [64][16][49][49] f32 (9,834,496)
//   452333568  : wqkv_t  [1536][512] u16 (1,572,864)
//   453906432  : wproj_t [512][512]  u16 (524,288)   total 454,430,720 B

typedef unsigned short u16;
typedef __attribute__((ext_vector_type(8))) short short8;
typedef __attribute__((ext_vector_type(4))) float floatx4;

#define B_WIN 2048
#define SEQ 49
#define DIM 512
#define NHEAD 16
#define HD 32
#define MROWS (B_WIN * SEQ)          // 100352
#define QTOT 51380224u               // 2048*16*49*32 elems (one Q or K plane set)
#define VOFF 102760448u              // elem offset of Vt planes ( = 2*QTOT)

__device__ __forceinline__ u16 f2bf(float x) {
    unsigned u = __float_as_uint(x);
    u += 0x7fffu + ((u >> 16) & 1u);   // RNE
    return (u16)(u >> 16);
}

__device__ __forceinline__ void async_ld16(const void* g, void* l) {
    __builtin_amdgcn_global_load_lds(
        (const __attribute__((address_space(1))) void*)g,
        (__attribute__((address_space(3))) void*)l, 16, 0, 0);
}

// ---------- conversion kernels ----------
__global__ void conv_f32_bf16(const float* __restrict__ in, u16* __restrict__ out, int n4) {
    int id = blockIdx.x * 256 + threadIdx.x;
    if (id >= n4) return;
    float4 v = ((const float4*)in)[id];
    uint2 o;
    o.x = (unsigned)f2bf(v.x) | ((unsigned)f2bf(v.y) << 16);
    o.y = (unsigned)f2bf(v.z) | ((unsigned)f2bf(v.w) << 16);
    *(uint2*)(out + (size_t)id * 4) = o;
}

// in: [512][Cn] f32 (k-major). out: [Cn][512] bf16 (n-major).
__global__ void transpose_conv(const float* __restrict__ in, u16* __restrict__ out, int Cn) {
    int id = blockIdx.x * 256 + threadIdx.x;
    if (id >= Cn * 512) return;
    int k = id & 511;
    int n = id >> 9;
    out[id] = f2bf(in[(size_t)k * Cn + n]);
}

// combined[w][h][i][j] = bias_table[rel_idx[i*49+j]][h] + mask[w][i][j]
__global__ void build_combined(const float* __restrict__ mask, const float* __restrict__ bias_table,
                               const int* __restrict__ rel_idx, float* __restrict__ cmb) {
    int id = blockIdx.x * 256 + threadIdx.x;    // 64*16*2401 = 2,458,624
    if (id >= 64 * 16 * 2401) return;
    int ij = id % 2401;
    int wh = id / 2401;
    int h = wh & 15, w = wh >> 4;
    cmb[id] = bias_table[rel_idx[ij] * NHEAD + h] + mask[(size_t)w * 2401 + ij];
}

// ---------- GEMM1: qkv = x @ qkv_w + b, scattered to per-head planes ----------
__global__ __launch_bounds__(256, 2)
void gemm_qkv(const u16* __restrict__ A, const u16* __restrict__ Bt,
              const float* __restrict__ bias, u16* __restrict__ qkvp) {
    const int K = 512;
    const int tid  = threadIdx.x;
    const int lane = tid & 63, wave = tid >> 6;
    const int quad = lane >> 4, l16 = lane & 15;
    const int wr = wave >> 1, wc = wave & 1;
    const int m0 = blockIdx.y * 128, n0 = blockIdx.x * 128;

    __shared__ u16 As[128 * 32];
    __shared__ u16 Bs[128 * 32];

    const int f0 = (wave * 2 + 0) * 512 + lane * 8;
    const int f1 = (wave * 2 + 1) * 512 + lane * 8;
    const int r0 = f0 >> 5, c0 = f0 & 31;
    const int r1 = f1 >> 5, c1 = f1 & 31;
    const u16* Ab = A + (size_t)m0 * K;
    const u16* Bb = Bt + (size_t)n0 * K;

    floatx4 acc[4][4] = {};

    for (int kt = 0; kt < K; kt += 32) {
        async_ld16(Ab + (size_t)r0 * K + kt + c0, &As[f0]);
        async_ld16(Ab + (size_t)r1 * K + kt + c1, &As[f1]);
        async_ld16(Bb + (size_t)r0 * K + kt + c0, &Bs[f0]);
        async_ld16(Bb + (size_t)r1 * K + kt + c1, &Bs[f1]);
        __syncthreads();
        short8 af[4], bf[4];
#pragma unroll
        for (int i = 0; i < 4; ++i)
            af[i] = *(const short8*)&As[(wr * 64 + i * 16 + l16) * 32 + quad * 8];
#pragma unroll
        for (int j = 0; j < 4; ++j)
            bf[j] = *(const short8*)&Bs[(wc * 64 + j * 16 + l16) * 32 + quad * 8];
#pragma unroll
        for (int i = 0; i < 4; ++i)
#pragma unroll
            for (int j = 0; j < 4; ++j)
                acc[i][j] = __builtin_amdgcn_mfma_f32_16x16x32_bf16(af[i], bf[j], acc[i][j], 0, 0, 0);
        __syncthreads();
    }

#pragma unroll
    for (int i = 0; i < 4; ++i) {
#pragma unroll
        for (int r = 0; r < 4; ++r) {
            int row = m0 + wr * 64 + i * 16 + quad * 4 + r;
            int b2 = (unsigned)row / 49u;
            int s  = row - b2 * 49;
#pragma unroll
            for (int j = 0; j < 4; ++j) {
                int col = n0 + wc * 64 + j * 16 + l16;
                int c   = col >> 9;            // 0=Q 1=K 2=V
                int rem = col & 511;
                int hh  = rem >> 5, d = rem & 31;
                float val = acc[i][j][r] + bias[col];
                size_t idx;
                if (c < 2) idx = (size_t)c * QTOT + (size_t)(b2 * 16 + hh) * 1568 + s * 32 + d;
                else       idx = VOFF + (size_t)(b2 * 16 + hh) * 2048 + d * 64 + s;
                qkvp[idx] = f2bf(val);
            }
        }
    }
}

// ---------- GEMM: C[M][N] = A[M][K](bf16) * Bt[N][K]^T + bias (f32 out) ----------
__global__ __launch_bounds__(256, 2)
void gemm_bt(const u16* __restrict__ A, const u16* __restrict__ Bt,
             const float* __restrict__ bias, float* __restrict__ Cout,
             int M, int N, int K) {
    const int tid  = threadIdx.x;
    const int lane = tid & 63, wave = tid >> 6;
    const int quad = lane >> 4, l16 = lane & 15;
    const int wr = wave >> 1, wc = wave & 1;
    const int m0 = blockIdx.y * 128, n0 = blockIdx.x * 128;

    __shared__ u16 As[128 * 32];
    __shared__ u16 Bs[128 * 32];

    const int f0 = (wave * 2 + 0) * 512 + lane * 8;
    const int f1 = (wave * 2 + 1) * 512 + lane * 8;
    const int r0 = f0 >> 5, c0 = f0 & 31;
    const int r1 = f1 >> 5, c1 = f1 & 31;
    const u16* Ab = A + (size_t)m0 * K;
    const u16* Bb = Bt + (size_t)n0 * K;

    floatx4 acc[4][4] = {};

    for (int kt = 0; kt < K; kt += 32) {
        async_ld16(Ab + (size_t)r0 * K + kt + c0, &As[f0]);
        async_ld16(Ab + (size_t)r1 * K + kt + c1, &As[f1]);
        async_ld16(Bb + (size_t)r0 * K + kt + c0, &Bs[f0]);
        async_ld16(Bb + (size_t)r1 * K + kt + c1, &Bs[f1]);
        __syncthreads();
        short8 af[4], bf[4];
#pragma unroll
        for (int i = 0; i < 4; ++i)
            af[i] = *(const short8*)&As[(wr * 64 + i * 16 + l16) * 32 + quad * 8];
#pragma unroll
        for (int j = 0; j < 4; ++j)
            bf[j] = *(const short8*)&Bs[(wc * 64 + j * 16 + l16) * 32 + quad * 8];
#pragma unroll
        for (int i = 0; i < 4; ++i)
#pragma unroll
            for (int j = 0; j < 4; ++j)
                acc[i][j] = __builtin_amdgcn_mfma_f32_16x16x32_bf16(af[i], bf[j], acc[i][j], 0, 0, 0);
        __syncthreads();
    }

#pragma unroll
    for (int i = 0; i < 4; ++i) {
#pragma unroll
        for (int j = 0; j < 4; ++j) {
            int col = n0 + wc * 64 + j * 16 + l16;
            float bv = bias[col];
#pragma unroll
            for (int r = 0; r < 4; ++r) {
                int row = m0 + wr * 64 + i * 16 + quad * 4 + r;
                Cout[(size_t)row * N + col] = acc[i][j][r] + bv;
            }
        }
    }
}

// ---------- attention: one wave per (b,h); direct global frags + register softmax ----------
__global__ __launch_bounds__(64, 4)
void attn2(const u16* __restrict__ qkvp, const float* __restrict__ cmb,
           u16* __restrict__ out) {
    const int bid = blockIdx.x;
    const int b = bid >> 4, h = bid & 15;
    const int lane = threadIdx.x;
    const int quad = lane >> 4, l16 = lane & 15;

    const u16* qb = qkvp + (size_t)(b * 16 + h) * 1568;
    const u16* kb = qb + QTOT;
    const u16* vb = qkvp + VOFF + (size_t)(b * 16 + h) * 2048;   // V^T [32][64]

    __shared__ u16 ps[64 * 72];        // probs, row stride 72 elems (144 B)

    short8 af[4], bfr[4];
#pragma unroll
    for (int i = 0; i < 4; ++i) {
        int r = i * 16 + l16; if (r > 48) r = 48;     // clamp pad rows (outputs discarded)
        af[i] = *(const short8*)(qb + r * 32 + quad * 8);
    }
#pragma unroll
    for (int j = 0; j < 4; ++j) {
        int n = j * 16 + l16; if (n > 48) n = 48;     // clamp pad cols (logits masked)
        bfr[j] = *(const short8*)(kb + n * 32 + quad * 8);
    }

    const float scale = 0.1767766952966369f;          // 32^-0.5
    const float* cb = cmb + (size_t)((b & 63) * 16 + h) * 2401;

#pragma unroll
    for (int i = 0; i < 4; ++i) {
        floatx4 accS[4] = {};
#pragma unroll
        for (int j = 0; j < 4; ++j)
            accS[j] = __builtin_amdgcn_mfma_f32_16x16x32_bf16(af[i], bfr[j], accS[j], 0, 0, 0);
        const int rbase = i * 16 + quad * 4;
#pragma unroll
        for (int r = 0; r < 4; ++r) {
            int row = rbase + r;
            int rc = row < 48 ? row : 48;             // keep table reads in bounds
            float x[4];
#pragma unroll
            for (int j = 0; j < 4; ++j) {
                int col = j * 16 + l16;
                x[j] = (col < SEQ) ? accS[j][r] * scale + cb[rc * 49 + col] : -3.0e38f;
            }
            float m = fmaxf(fmaxf(x[0], x[1]), fmaxf(x[2], x[3]));
#pragma unroll
            for (int off = 1; off < 16; off <<= 1) m = fmaxf(m, __shfl_xor(m, off));
            float e[4], s = 0.f;
#pragma unroll
            for (int j = 0; j < 4; ++j) { e[j] = __expf(x[j] - m); s += e[j]; }
#pragma unroll
            for (int off = 1; off < 16; off <<= 1) s += __shfl_xor(s, off);
            float inv = __builtin_amdgcn_rcpf(s);
#pragma unroll
            for (int j = 0; j < 4; ++j)
                ps[row * 72 + j * 16 + l16] = f2bf(e[j] * inv);
        }
    }
    __syncthreads();

    // PV: O[64x32] = P[64x64] * V[64x32] via A=ps rows, B=V^T rows
    floatx4 accO[4][2] = {};
#pragma unroll
    for (int kt = 0; kt < 2; ++kt) {
        short8 pf[4], vf[2];
#pragma unroll
        for (int i = 0; i < 4; ++i)
            pf[i] = *(const short8*)&ps[(i * 16 + l16) * 72 + kt * 32 + quad * 8];
#pragma unroll
        for (int jn = 0; jn < 2; ++jn)
            vf[jn] = *(const short8*)(vb + (jn * 16 + l16) * 64 + kt * 32 + quad * 8);
#pragma unroll
        for (int i = 0; i < 4; ++i)
#pragma unroll
            for (int jn = 0; jn < 2; ++jn)
                accO[i][jn] = __builtin_amdgcn_mfma_f32_16x16x32_bf16(pf[i], vf[jn], accO[i][jn], 0, 0, 0);
    }

    u16* op = out + (size_t)b * SEQ * DIM + h * HD;
#pragma unroll
    for (int i = 0; i < 4; ++i)
#pragma unroll
        for (int jn = 0; jn < 2; ++jn)
#pragma unroll
            for (int r = 0; r < 4; ++r) {
                int row = i * 16 + quad * 4 + r;
                if (row < SEQ)
                    op[(size_t)row * DIM + jn * 16 + l16] = f2bf(accO[i][jn][r]);
            }
}

extern "C" void kernel_launch(void* const* d_in, const int* in_sizes, int n_in,
                              void* d_out, int out_size, void* d_ws, size_t ws_size,
                              hipStream_t stream) {
    const float* x         = (const float*)d_in[0];
    const float* mask      = (const float*)d_in[1];
    const float* qkv_w     = (const float*)d_in[2];
    const float* qkv_b     = (const float*)d_in[3];
    const float* proj_w    = (const float*)d_in[4];
    const float* proj_b    = (const float*)d_in[5];
    const float* bias_tab  = (const float*)d_in[6];
    const int*   rel_idx   = (const int*)d_in[7];
    float* out = (float*)d_out;

    char* ws = (char*)d_ws;
    u16*   xbf     = (u16*)(ws + 0);               // reused as attn_out
    u16*   qkvp    = (u16*)(ws + 102760448);
    float* cmb     = (float*)(ws + 442499072);
    u16*   wqkv_t  = (u16*)(ws + 452333568);
    u16*   wproj_t = (u16*)(ws + 453906432);

    // x -> bf16 (51,380,224 elems = 12,845,056 float4s)
    conv_f32_bf16<<<50176, 256, 0, stream>>>(x, xbf, 12845056);
    // weight transposes
    transpose_conv<<<3072, 256, 0, stream>>>(qkv_w, wqkv_t, 1536);
    transpose_conv<<<1024, 256, 0, stream>>>(proj_w, wproj_t, 512);
    // combined bias+mask table
    build_combined<<<9604, 256, 0, stream>>>(mask, bias_tab, rel_idx, cmb);
    // qkv GEMM -> scattered per-head planes
    gemm_qkv<<<dim3(12, 784), 256, 0, stream>>>(xbf, wqkv_t, qkv_b, qkvp);
    // attention -> attn_out (reuses xbf)
    attn2<<<B_WIN * NHEAD, 64, 0, stream>>>(qkvp, cmb, xbf);
    // out = attn @ proj_w + proj_b
    gemm_bt<<<dim3(4, 784), 256, 0, stream>>>(xbf, wproj_t, proj_b, out,
                                              MROWS, 512, 512);
}